// Round 3
// baseline (280.601 us; speedup 1.0000x reference)
//
#include <hip/hip_runtime.h>
#include <stdint.h>

#define BH   (8 * 4096)
#define HDIM 1024
#define NIDX 65536
#define NSEG 8192
#define KD   1024
#define ND   1024

typedef __bf16 bf16x8 __attribute__((ext_vector_type(8)));
typedef float  f32x4  __attribute__((ext_vector_type(4)));

__device__ __forceinline__ unsigned short f2bf(float f) {
  unsigned int u = __float_as_uint(f);
  u += 0x7fffu + ((u >> 16) & 1u);   // RNE
  return (unsigned short)(u >> 16);
}

// ---------------- Kernel 0: W_dense fp32 -> bf16 ----------------
__global__ void convw_kernel(const float* __restrict__ W, unsigned short* __restrict__ Wb) {
  int i = (blockIdx.x * 256 + threadIdx.x) * 4;
  float4 v = *(const float4*)(W + i);
  ushort4 o;
  o.x = f2bf(v.x); o.y = f2bf(v.y); o.z = f2bf(v.z); o.w = f2bf(v.w);
  *(ushort4*)(Wb + i) = o;
}

// ---------------- Kernel 1: segment boundaries ----------------
__global__ void bounds_kernel(const int* __restrict__ seg, int* __restrict__ starts) {
  int i = blockIdx.x * 256 + threadIdx.x;
  if (i > NIDX) return;
  int prev = (i == 0) ? -1 : seg[i - 1];
  int cur  = (i == NIDX) ? NSEG : seg[i];
  for (int g = prev + 1; g <= cur; ++g) starts[g] = i;
}

// ---------------- Kernel 2: segment mean -> h (bf16), init out ----------------
__global__ void segmean_kernel(const float* __restrict__ hid,
                               const int* __restrict__ indices,
                               const int* __restrict__ starts,
                               unsigned short* __restrict__ hb,
                               float* __restrict__ out,
                               const float* __restrict__ b_proj) {
  const int g = blockIdx.x;
  const int t = threadIdx.x;
  const int start = starts[g];
  const int end   = starts[g + 1];

  float4 acc = make_float4(0.f, 0.f, 0.f, 0.f);
  for (int i = start; i < end; ++i) {
    int r = indices[i];
    float4 v = *(const float4*)(hid + (size_t)r * HDIM + t * 4);
    acc.x += v.x; acc.y += v.y; acc.z += v.z; acc.w += v.w;
  }
  const float inv = 1.0f / fmaxf((float)(end - start), 1.0f);
  ushort4 o;
  o.x = f2bf(acc.x * inv); o.y = f2bf(acc.y * inv);
  o.z = f2bf(acc.z * inv); o.w = f2bf(acc.w * inv);
  *(ushort4*)(hb + (size_t)g * HDIM + t * 4) = o;

  if (t == 0) out[g] = b_proj[0];
}

// ---------------- Kernel 3: barrier-free GEMM + bias + erf-GELU + proj ----------
// Per-wave 64x64 C tile, NO LDS, NO __syncthreads. A/B fragments loaded straight
// from global (L2/L3-resident) as 16B/lane dwordx4; even/odd register double-buffer.
// Block's 4 waves share the same A-tile (same mt) -> L1 reuse.
__global__ void __launch_bounds__(256)
gemm_gelu_proj_kernel(const unsigned short* __restrict__ A,   // h  [NSEG,KD] bf16
                      const unsigned short* __restrict__ Bw,  // W  [ND,KD]  bf16
                      const float* __restrict__ b_dense,
                      const float* __restrict__ w_proj,
                      float* __restrict__ out) {
  const int tid  = threadIdx.x;
  const int lane = tid & 63;
  const int wave = tid >> 6;
  const int w    = blockIdx.x * 4 + wave;   // 0..2047
  const int mt   = w >> 4;                  // 0..127 (M tiles of 64)
  const int nt   = w & 15;                  // 0..15  (N tiles of 64)
  const int lr   = lane & 15;
  const int quad = lane >> 4;               // 0..3

  // per-fragment base pointers (16B aligned: row*2048B + quad*16B)
  const unsigned short* pA[4];
  const unsigned short* pB[4];
#pragma unroll
  for (int i = 0; i < 4; ++i) {
    pA[i] = A  + (size_t)(mt * 64 + i * 16 + lr) * KD + quad * 8;
    pB[i] = Bw + (size_t)(nt * 64 + i * 16 + lr) * KD + quad * 8;
  }

  f32x4 acc[4][4];
#pragma unroll
  for (int mi = 0; mi < 4; ++mi)
#pragma unroll
    for (int ni = 0; ni < 4; ++ni) {
      acc[mi][ni][0] = 0.f; acc[mi][ni][1] = 0.f;
      acc[mi][ni][2] = 0.f; acc[mi][ni][3] = 0.f;
    }

  bf16x8 a0[4], b0[4], a1[4], b1[4];
#pragma unroll
  for (int i = 0; i < 4; ++i) {
    a0[i] = *(const bf16x8*)(pA[i]);
    b0[i] = *(const bf16x8*)(pB[i]);
  }

#pragma unroll 1
  for (int kt = 0; kt < 16; ++kt) {        // 16 iters x 2 k-steps of 32
    // prefetch odd k-step
#pragma unroll
    for (int i = 0; i < 4; ++i) {
      a1[i] = *(const bf16x8*)(pA[i] + 32);
      b1[i] = *(const bf16x8*)(pB[i] + 32);
    }
#pragma unroll
    for (int mi = 0; mi < 4; ++mi)
#pragma unroll
      for (int ni = 0; ni < 4; ++ni)
        acc[mi][ni] = __builtin_amdgcn_mfma_f32_16x16x32_bf16(a0[mi], b0[ni], acc[mi][ni], 0, 0, 0);
    // prefetch next even k-step
    if (kt != 15) {
#pragma unroll
      for (int i = 0; i < 4; ++i) {
        a0[i] = *(const bf16x8*)(pA[i] + 64);
        b0[i] = *(const bf16x8*)(pB[i] + 64);
      }
    }
#pragma unroll
    for (int mi = 0; mi < 4; ++mi)
#pragma unroll
      for (int ni = 0; ni < 4; ++ni)
        acc[mi][ni] = __builtin_amdgcn_mfma_f32_16x16x32_bf16(a1[mi], b1[ni], acc[mi][ni], 0, 0, 0);
#pragma unroll
    for (int i = 0; i < 4; ++i) { pA[i] += 64; pB[i] += 64; }
  }

  // Epilogue: bias + exact erf-GELU + w_proj weighting; reduce over this wave's
  // 64 columns (ni and lr groups), one atomicAdd per C-row partial.
#pragma unroll
  for (int mi = 0; mi < 4; ++mi) {
    float rp[4] = {0.f, 0.f, 0.f, 0.f};
#pragma unroll
    for (int ni = 0; ni < 4; ++ni) {
      int col  = nt * 64 + ni * 16 + lr;
      float bd = b_dense[col];
      float wp = w_proj[col];
#pragma unroll
      for (int r = 0; r < 4; ++r) {
        float v  = acc[mi][ni][r] + bd;
        float gl = 0.5f * v * (1.0f + erff(v * 0.70710678118654752f));
        rp[r] += gl * wp;
      }
    }
#pragma unroll
    for (int r = 0; r < 4; ++r) {
      float c = rp[r];
      c += __shfl_xor(c, 1);
      c += __shfl_xor(c, 2);
      c += __shfl_xor(c, 4);
      c += __shfl_xor(c, 8);
      if (lr == 0)
        atomicAdd(out + (mt * 64 + mi * 16 + quad * 4 + r), c);
    }
  }
}

extern "C" void kernel_launch(void* const* d_in, const int* in_sizes, int n_in,
                              void* d_out, int out_size, void* d_ws, size_t ws_size,
                              hipStream_t stream) {
  const float* hid     = (const float*)d_in[0];
  const int*   indices = (const int*)d_in[1];
  const int*   seg     = (const int*)d_in[2];
  const float* W_dense = (const float*)d_in[3];
  const float* b_dense = (const float*)d_in[4];
  const float* W_proj  = (const float*)d_in[5];
  const float* b_proj  = (const float*)d_in[6];
  float* out = (float*)d_out;

  // ws layout: h_bf16 [NSEG*KD] (16 MiB) | W_bf16 [ND*KD] (2 MiB) | starts [NSEG+1]
  unsigned short* hb     = (unsigned short*)d_ws;
  unsigned short* Wb     = (unsigned short*)((char*)d_ws + (size_t)NSEG * KD * 2);
  int*            starts = (int*)((char*)d_ws + (size_t)NSEG * KD * 2 + (size_t)ND * KD * 2);

  convw_kernel<<<dim3((ND * KD) / 1024), 256, 0, stream>>>(W_dense, Wb);
  bounds_kernel<<<dim3((NIDX + 256) / 256), 256, 0, stream>>>(seg, starts);
  segmean_kernel<<<dim3(NSEG), 256, 0, stream>>>(hid, indices, starts, hb, out, b_proj);
  gemm_gelu_proj_kernel<<<dim3((NSEG / 64) * (ND / 64) / 4), 256, 0, stream>>>(hb, Wb, b_dense, W_proj, out);
}

// Round 4
// 242.493 us; speedup vs baseline: 1.1572x; 1.1572x over previous
//
#include <hip/hip_runtime.h>
#include <stdint.h>

#define BH   (8 * 4096)
#define HDIM 1024
#define NIDX 65536
#define NSEG 8192
#define KD   1024
#define ND   1024

typedef __bf16 bf16x8 __attribute__((ext_vector_type(8)));
typedef float  f32x4  __attribute__((ext_vector_type(4)));

__device__ __forceinline__ unsigned short f2bf(float f) {
  unsigned int u = __float_as_uint(f);
  u += 0x7fffu + ((u >> 16) & 1u);   // RNE
  return (unsigned short)(u >> 16);
}

__device__ __forceinline__ void async16(const void* g, void* l) {
  __builtin_amdgcn_global_load_lds(
      (const __attribute__((address_space(1))) void*)g,
      (__attribute__((address_space(3))) void*)l,
      16, 0, 0);
}

// ---------------- Kernel 0: fused W conv (bf16) + segment boundaries ----------------
// blocks [0,1024): convert W_dense fp32->bf16 (4 elem/thread)
// blocks [1024,1281): bounds — starts[g] = first i with seg[i] >= g
__global__ void prep_kernel(const float* __restrict__ W, unsigned short* __restrict__ Wb,
                            const int* __restrict__ seg, int* __restrict__ starts) {
  if (blockIdx.x < 1024) {
    int i = (blockIdx.x * 256 + threadIdx.x) * 4;
    float4 v = *(const float4*)(W + i);
    ushort4 o;
    o.x = f2bf(v.x); o.y = f2bf(v.y); o.z = f2bf(v.z); o.w = f2bf(v.w);
    *(ushort4*)(Wb + i) = o;
  } else {
    int i = (blockIdx.x - 1024) * 256 + threadIdx.x;
    if (i > NIDX) return;
    int prev = (i == 0) ? -1 : seg[i - 1];
    int cur  = (i == NIDX) ? NSEG : seg[i];
    for (int g = prev + 1; g <= cur; ++g) starts[g] = i;
  }
}

// ---------------- Kernel 1: segment mean -> h (bf16), init out ----------------
// one block per segment; 256 threads x float4 covers H=1024.
// 4-way row unroll: 4 independent 4KB row-reads in flight per block.
__global__ void segmean_kernel(const float* __restrict__ hid,
                               const int* __restrict__ indices,
                               const int* __restrict__ starts,
                               unsigned short* __restrict__ hb,
                               float* __restrict__ out,
                               const float* __restrict__ b_proj) {
  const int g = blockIdx.x;
  const int t = threadIdx.x;
  const int start = starts[g];
  const int end   = starts[g + 1];
  const int col   = t * 4;

  float4 a0 = make_float4(0.f, 0.f, 0.f, 0.f);
  float4 a1 = a0, a2 = a0, a3 = a0;

  int i = start;
  for (; i + 4 <= end; i += 4) {
    int r0 = indices[i];
    int r1 = indices[i + 1];
    int r2 = indices[i + 2];
    int r3 = indices[i + 3];
    float4 v0 = *(const float4*)(hid + (size_t)r0 * HDIM + col);
    float4 v1 = *(const float4*)(hid + (size_t)r1 * HDIM + col);
    float4 v2 = *(const float4*)(hid + (size_t)r2 * HDIM + col);
    float4 v3 = *(const float4*)(hid + (size_t)r3 * HDIM + col);
    a0.x += v0.x; a0.y += v0.y; a0.z += v0.z; a0.w += v0.w;
    a1.x += v1.x; a1.y += v1.y; a1.z += v1.z; a1.w += v1.w;
    a2.x += v2.x; a2.y += v2.y; a2.z += v2.z; a2.w += v2.w;
    a3.x += v3.x; a3.y += v3.y; a3.z += v3.z; a3.w += v3.w;
  }
  for (; i < end; ++i) {
    int r = indices[i];
    float4 v = *(const float4*)(hid + (size_t)r * HDIM + col);
    a0.x += v.x; a0.y += v.y; a0.z += v.z; a0.w += v.w;
  }
  a0.x += a1.x + a2.x + a3.x;
  a0.y += a1.y + a2.y + a3.y;
  a0.z += a1.z + a2.z + a3.z;
  a0.w += a1.w + a2.w + a3.w;

  const float inv = 1.0f / fmaxf((float)(end - start), 1.0f);
  ushort4 o;
  o.x = f2bf(a0.x * inv); o.y = f2bf(a0.y * inv);
  o.z = f2bf(a0.z * inv); o.w = f2bf(a0.w * inv);
  *(ushort4*)(hb + (size_t)g * HDIM + col) = o;

  if (t == 0) out[g] = b_proj[0];
}

// ---------------- Kernel 2: fused GEMM + bias + erf-GELU + proj (round-2 best) ----
// C tile 128x64, BK=32, 256 threads = 4 waves (2x2), wave tile 64x32 (4x2 MFMA 16x16x32)
// LDS k-chunk swizzle applied at the global-source side (DMA dst stays lane-contiguous).
__global__ void __launch_bounds__(256)
gemm_gelu_proj_kernel(const unsigned short* __restrict__ A,   // h  [NSEG,KD] bf16
                      const unsigned short* __restrict__ Bw,  // W  [ND,KD]  bf16
                      const float* __restrict__ b_dense,
                      const float* __restrict__ w_proj,
                      float* __restrict__ out) {
  __shared__ alignas(16) unsigned short As[128 * 32];  // 8 KiB
  __shared__ alignas(16) unsigned short Bs[64 * 32];   // 4 KiB

  const int tid  = threadIdx.x;
  const int lane = tid & 63;
  const int wave = tid >> 6;
  const int wm   = wave >> 1;
  const int wn   = wave & 1;
  const int m0   = blockIdx.x * 128;
  const int n0   = blockIdx.y * 64;
  const int lr   = lane & 15;
  const int quad = lane >> 4;

  f32x4 acc[4][2];
#pragma unroll
  for (int mi = 0; mi < 4; ++mi)
#pragma unroll
    for (int ni = 0; ni < 2; ++ni) {
      acc[mi][ni][0] = 0.f; acc[mi][ni][1] = 0.f;
      acc[mi][ni][2] = 0.f; acc[mi][ni][3] = 0.f;
    }

  for (int kt = 0; kt < KD / 32; ++kt) {
    const int k0 = kt * 32;
#pragma unroll
    for (int j = 0; j < 2; ++j) {          // A chunks (512 x 16B)
      int c   = j * 256 + wave * 64 + lane;
      int row = c >> 2, sl = c & 3;
      int kcg = sl ^ ((row >> 1) & 3);
      async16(A + (size_t)(m0 + row) * KD + k0 + kcg * 8,
              (char*)As + (j * 256 + wave * 64) * 16);
    }
    {                                       // B chunks (256 x 16B)
      int c   = wave * 64 + lane;
      int row = c >> 2, sl = c & 3;
      int kcg = sl ^ ((row >> 1) & 3);
      async16(Bw + (size_t)(n0 + row) * KD + k0 + kcg * 8,
              (char*)Bs + (wave * 64) * 16);
    }
    __syncthreads();

    bf16x8 af[4], bf_[2];
#pragma unroll
    for (int i = 0; i < 4; ++i) {
      int ra  = wm * 64 + i * 16 + lr;
      int sla = quad ^ ((ra >> 1) & 3);
      af[i] = *(const bf16x8*)(As + ra * 32 + sla * 8);
    }
#pragma unroll
    for (int i = 0; i < 2; ++i) {
      int rb  = wn * 32 + i * 16 + lr;
      int slb = quad ^ ((rb >> 1) & 3);
      bf_[i] = *(const bf16x8*)(Bs + rb * 32 + slb * 8);
    }
#pragma unroll
    for (int mi = 0; mi < 4; ++mi)
#pragma unroll
      for (int ni = 0; ni < 2; ++ni)
        acc[mi][ni] = __builtin_amdgcn_mfma_f32_16x16x32_bf16(af[mi], bf_[ni], acc[mi][ni], 0, 0, 0);
    __syncthreads();
  }

#pragma unroll
  for (int mi = 0; mi < 4; ++mi) {
    float rp[4] = {0.f, 0.f, 0.f, 0.f};
#pragma unroll
    for (int ni = 0; ni < 2; ++ni) {
      int col  = n0 + wn * 32 + ni * 16 + lr;
      float bd = b_dense[col];
      float wp = w_proj[col];
#pragma unroll
      for (int r = 0; r < 4; ++r) {
        float v  = acc[mi][ni][r] + bd;
        float gl = 0.5f * v * (1.0f + erff(v * 0.70710678118654752f));
        rp[r] += gl * wp;
      }
    }
#pragma unroll
    for (int r = 0; r < 4; ++r) {
      float c = rp[r];
      c += __shfl_xor(c, 1);
      c += __shfl_xor(c, 2);
      c += __shfl_xor(c, 4);
      c += __shfl_xor(c, 8);
      if (lr == 0)
        atomicAdd(out + (m0 + wm * 64 + mi * 16 + quad * 4 + r), c);
    }
  }
}

extern "C" void kernel_launch(void* const* d_in, const int* in_sizes, int n_in,
                              void* d_out, int out_size, void* d_ws, size_t ws_size,
                              hipStream_t stream) {
  const float* hid     = (const float*)d_in[0];
  const int*   indices = (const int*)d_in[1];
  const int*   seg     = (const int*)d_in[2];
  const float* W_dense = (const float*)d_in[3];
  const float* b_dense = (const float*)d_in[4];
  const float* W_proj  = (const float*)d_in[5];
  const float* b_proj  = (const float*)d_in[6];
  float* out = (float*)d_out;

  // ws layout: h_bf16 [NSEG*KD] (16 MiB) | W_bf16 [ND*KD] (2 MiB) | starts [NSEG+1]
  unsigned short* hb     = (unsigned short*)d_ws;
  unsigned short* Wb     = (unsigned short*)((char*)d_ws + (size_t)NSEG * KD * 2);
  int*            starts = (int*)((char*)d_ws + (size_t)NSEG * KD * 2 + (size_t)ND * KD * 2);

  prep_kernel<<<dim3(1024 + (NIDX + 256) / 256), 256, 0, stream>>>(W_dense, Wb, seg, starts);
  segmean_kernel<<<dim3(NSEG), 256, 0, stream>>>(hid, indices, starts, hb, out, b_proj);
  gemm_gelu_proj_kernel<<<dim3(NSEG / 128, ND / 64), 256, 0, stream>>>(hb, Wb, b_dense, W_proj, out);
}

// Round 5
// 241.051 us; speedup vs baseline: 1.1641x; 1.0060x over previous
//
#include <hip/hip_runtime.h>
#include <stdint.h>

#define BH   (8 * 4096)
#define HDIM 1024
#define NIDX 65536
#define NSEG 8192
#define KD   1024
#define ND   1024

typedef __bf16 bf16x8 __attribute__((ext_vector_type(8)));
typedef float  f32x4  __attribute__((ext_vector_type(4)));

__device__ __forceinline__ unsigned short f2bf(float f) {
  unsigned int u = __float_as_uint(f);
  u += 0x7fffu + ((u >> 16) & 1u);   // RNE
  return (unsigned short)(u >> 16);
}

__device__ __forceinline__ void async16(const void* g, void* l) {
  __builtin_amdgcn_global_load_lds(
      (const __attribute__((address_space(1))) void*)g,
      (__attribute__((address_space(3))) void*)l,
      16, 0, 0);
}

// ---------------- Kernel 0: fused W conv (bf16) + segment boundaries ----------------
__global__ void prep_kernel(const float* __restrict__ W, unsigned short* __restrict__ Wb,
                            const int* __restrict__ seg, int* __restrict__ starts) {
  if (blockIdx.x < 1024) {
    int i = (blockIdx.x * 256 + threadIdx.x) * 4;
    float4 v = *(const float4*)(W + i);
    ushort4 o;
    o.x = f2bf(v.x); o.y = f2bf(v.y); o.z = f2bf(v.z); o.w = f2bf(v.w);
    *(ushort4*)(Wb + i) = o;
  } else {
    int i = (blockIdx.x - 1024) * 256 + threadIdx.x;
    if (i > NIDX) return;
    int prev = (i == 0) ? -1 : seg[i - 1];
    int cur  = (i == NIDX) ? NSEG : seg[i];
    for (int g = prev + 1; g <= cur; ++g) starts[g] = i;
  }
}

// ---------------- Kernel 1: segment mean -> h (bf16), init out ----------------
__global__ void segmean_kernel(const float* __restrict__ hid,
                               const int* __restrict__ indices,
                               const int* __restrict__ starts,
                               unsigned short* __restrict__ hb,
                               float* __restrict__ out,
                               const float* __restrict__ b_proj) {
  const int g = blockIdx.x;
  const int t = threadIdx.x;
  const int start = starts[g];
  const int end   = starts[g + 1];
  const int col   = t * 4;

  float4 a0 = make_float4(0.f, 0.f, 0.f, 0.f);
  float4 a1 = a0, a2 = a0, a3 = a0;

  int i = start;
  for (; i + 4 <= end; i += 4) {
    int r0 = indices[i];
    int r1 = indices[i + 1];
    int r2 = indices[i + 2];
    int r3 = indices[i + 3];
    float4 v0 = *(const float4*)(hid + (size_t)r0 * HDIM + col);
    float4 v1 = *(const float4*)(hid + (size_t)r1 * HDIM + col);
    float4 v2 = *(const float4*)(hid + (size_t)r2 * HDIM + col);
    float4 v3 = *(const float4*)(hid + (size_t)r3 * HDIM + col);
    a0.x += v0.x; a0.y += v0.y; a0.z += v0.z; a0.w += v0.w;
    a1.x += v1.x; a1.y += v1.y; a1.z += v1.z; a1.w += v1.w;
    a2.x += v2.x; a2.y += v2.y; a2.z += v2.z; a2.w += v2.w;
    a3.x += v3.x; a3.y += v3.y; a3.z += v3.z; a3.w += v3.w;
  }
  for (; i < end; ++i) {
    int r = indices[i];
    float4 v = *(const float4*)(hid + (size_t)r * HDIM + col);
    a0.x += v.x; a0.y += v.y; a0.z += v.z; a0.w += v.w;
  }
  a0.x += a1.x + a2.x + a3.x;
  a0.y += a1.y + a2.y + a3.y;
  a0.z += a1.z + a2.z + a3.z;
  a0.w += a1.w + a2.w + a3.w;

  const float inv = 1.0f / fmaxf((float)(end - start), 1.0f);
  ushort4 o;
  o.x = f2bf(a0.x * inv); o.y = f2bf(a0.y * inv);
  o.z = f2bf(a0.z * inv); o.w = f2bf(a0.w * inv);
  *(ushort4*)(hb + (size_t)g * HDIM + col) = o;

  if (t == 0) out[g] = b_proj[0];
}

// ---------------- Kernel 2: fused GEMM + bias + erf-GELU + proj ----------------
// C tile 128x64, BK=64 (2 k-steps of 32 per staged tile), 256 threads = 4 waves (2x2),
// wave tile 64x32 (4x2 MFMA 16x16x32). 16 K-iterations, 2 barriers each (was 32x2).
// Swizzle: LDS row = 8 chunks of 16B; global chunk kc stored at slot kc ^ (row&7)
// -> ds_read_b128 spreads over all 32 banks, 2 lanes per 4-bank group (free).
__global__ void __launch_bounds__(256)
gemm_gelu_proj_kernel(const unsigned short* __restrict__ A,   // h  [NSEG,KD] bf16
                      const unsigned short* __restrict__ Bw,  // W  [ND,KD]  bf16
                      const float* __restrict__ b_dense,
                      const float* __restrict__ w_proj,
                      float* __restrict__ out) {
  __shared__ alignas(16) unsigned short As[128 * 64];  // 16 KiB
  __shared__ alignas(16) unsigned short Bs[64 * 64];   // 8 KiB

  const int tid  = threadIdx.x;
  const int lane = tid & 63;
  const int wave = tid >> 6;
  const int wm   = wave >> 1;
  const int wn   = wave & 1;
  const int m0   = blockIdx.x * 128;
  const int n0   = blockIdx.y * 64;
  const int lr   = lane & 15;
  const int quad = lane >> 4;

  f32x4 acc[4][2];
#pragma unroll
  for (int mi = 0; mi < 4; ++mi)
#pragma unroll
    for (int ni = 0; ni < 2; ++ni) {
      acc[mi][ni][0] = 0.f; acc[mi][ni][1] = 0.f;
      acc[mi][ni][2] = 0.f; acc[mi][ni][3] = 0.f;
    }

  for (int kt = 0; kt < KD / 64; ++kt) {
    const int k0 = kt * 64;
    // A tile: 128x64 bf16 = 1024 chunks of 16B; 4 per thread
#pragma unroll
    for (int j = 0; j < 4; ++j) {
      int c   = j * 256 + wave * 64 + lane;
      int row = c >> 3, sl = c & 7;
      int kcg = sl ^ (row & 7);
      async16(A + (size_t)(m0 + row) * KD + k0 + kcg * 8,
              (char*)As + (j * 256 + wave * 64) * 16);
    }
    // B tile: 64x64 bf16 = 512 chunks; 2 per thread
#pragma unroll
    for (int j = 0; j < 2; ++j) {
      int c   = j * 256 + wave * 64 + lane;
      int row = c >> 3, sl = c & 7;
      int kcg = sl ^ (row & 7);
      async16(Bw + (size_t)(n0 + row) * KD + k0 + kcg * 8,
              (char*)Bs + (j * 256 + wave * 64) * 16);
    }
    __syncthreads();

#pragma unroll
    for (int s = 0; s < 2; ++s) {           // two k-steps of 32
      bf16x8 af[4], bf_[2];
#pragma unroll
      for (int i = 0; i < 4; ++i) {
        int ra   = wm * 64 + i * 16 + lr;
        int slot = (s * 4 + quad) ^ (ra & 7);
        af[i] = *(const bf16x8*)(As + ra * 64 + slot * 8);
      }
#pragma unroll
      for (int i = 0; i < 2; ++i) {
        int rb   = wn * 32 + i * 16 + lr;
        int slot = (s * 4 + quad) ^ (rb & 7);
        bf_[i] = *(const bf16x8*)(Bs + rb * 64 + slot * 8);
      }
#pragma unroll
      for (int mi = 0; mi < 4; ++mi)
#pragma unroll
        for (int ni = 0; ni < 2; ++ni)
          acc[mi][ni] = __builtin_amdgcn_mfma_f32_16x16x32_bf16(af[mi], bf_[ni], acc[mi][ni], 0, 0, 0);
    }
    __syncthreads();
  }

  // Epilogue: bias + exact erf-GELU + w_proj weighting; per-row partial over 64 cols
#pragma unroll
  for (int mi = 0; mi < 4; ++mi) {
    float rp[4] = {0.f, 0.f, 0.f, 0.f};
#pragma unroll
    for (int ni = 0; ni < 2; ++ni) {
      int col  = n0 + wn * 32 + ni * 16 + lr;
      float bd = b_dense[col];
      float wp = w_proj[col];
#pragma unroll
      for (int r = 0; r < 4; ++r) {
        float v  = acc[mi][ni][r] + bd;
        float gl = 0.5f * v * (1.0f + erff(v * 0.70710678118654752f));
        rp[r] += gl * wp;
      }
    }
#pragma unroll
    for (int r = 0; r < 4; ++r) {
      float c = rp[r];
      c += __shfl_xor(c, 1);
      c += __shfl_xor(c, 2);
      c += __shfl_xor(c, 4);
      c += __shfl_xor(c, 8);
      if (lr == 0)
        atomicAdd(out + (m0 + wm * 64 + mi * 16 + quad * 4 + r), c);
    }
  }
}

extern "C" void kernel_launch(void* const* d_in, const int* in_sizes, int n_in,
                              void* d_out, int out_size, void* d_ws, size_t ws_size,
                              hipStream_t stream) {
  const float* hid     = (const float*)d_in[0];
  const int*   indices = (const int*)d_in[1];
  const int*   seg     = (const int*)d_in[2];
  const float* W_dense = (const float*)d_in[3];
  const float* b_dense = (const float*)d_in[4];
  const float* W_proj  = (const float*)d_in[5];
  const float* b_proj  = (const float*)d_in[6];
  float* out = (float*)d_out;

  // ws layout: h_bf16 [NSEG*KD] (16 MiB) | W_bf16 [ND*KD] (2 MiB) | starts [NSEG+1]
  unsigned short* hb     = (unsigned short*)d_ws;
  unsigned short* Wb     = (unsigned short*)((char*)d_ws + (size_t)NSEG * KD * 2);
  int*            starts = (int*)((char*)d_ws + (size_t)NSEG * KD * 2 + (size_t)ND * KD * 2);

  prep_kernel<<<dim3(1024 + (NIDX + 256) / 256), 256, 0, stream>>>(W_dense, Wb, seg, starts);
  segmean_kernel<<<dim3(NSEG), 256, 0, stream>>>(hid, indices, starts, hb, out, b_proj);
  gemm_gelu_proj_kernel<<<dim3(NSEG / 128, ND / 64), 256, 0, stream>>>(hb, Wb, b_dense, W_proj, out);
}

// Round 6
// 235.250 us; speedup vs baseline: 1.1928x; 1.0247x over previous
//
#include <hip/hip_runtime.h>
#include <stdint.h>

#define BH   (8 * 4096)
#define HDIM 1024
#define NIDX 65536
#define NSEG 8192
#define KD   1024
#define ND   1024

typedef __bf16 bf16x8 __attribute__((ext_vector_type(8)));
typedef float  f32x4  __attribute__((ext_vector_type(4)));

__device__ __forceinline__ unsigned short f2bf(float f) {
  unsigned int u = __float_as_uint(f);
  u += 0x7fffu + ((u >> 16) & 1u);   // RNE
  return (unsigned short)(u >> 16);
}

__device__ __forceinline__ void async16(const void* g, void* l) {
  __builtin_amdgcn_global_load_lds(
      (const __attribute__((address_space(1))) void*)g,
      (__attribute__((address_space(3))) void*)l,
      16, 0, 0);
}

// ---------------- Kernel 0: fused W conv (bf16) + segment boundaries ----------------
__global__ void prep_kernel(const float* __restrict__ W, unsigned short* __restrict__ Wb,
                            const int* __restrict__ seg, int* __restrict__ starts) {
  if (blockIdx.x < 1024) {
    int i = (blockIdx.x * 256 + threadIdx.x) * 4;
    float4 v = *(const float4*)(W + i);
    ushort4 o;
    o.x = f2bf(v.x); o.y = f2bf(v.y); o.z = f2bf(v.z); o.w = f2bf(v.w);
    *(ushort4*)(Wb + i) = o;
  } else {
    int i = (blockIdx.x - 1024) * 256 + threadIdx.x;
    if (i > NIDX) return;
    int prev = (i == 0) ? -1 : seg[i - 1];
    int cur  = (i == NIDX) ? NSEG : seg[i];
    for (int g = prev + 1; g <= cur; ++g) starts[g] = i;
  }
}

// ---------------- Kernel 1: segment mean -> h (bf16), init out ----------------
__global__ void segmean_kernel(const float* __restrict__ hid,
                               const int* __restrict__ indices,
                               const int* __restrict__ starts,
                               unsigned short* __restrict__ hb,
                               float* __restrict__ out,
                               const float* __restrict__ b_proj) {
  const int g = blockIdx.x;
  const int t = threadIdx.x;
  const int start = starts[g];
  const int end   = starts[g + 1];
  const int col   = t * 4;

  float4 a0 = make_float4(0.f, 0.f, 0.f, 0.f);
  float4 a1 = a0, a2 = a0, a3 = a0;

  int i = start;
  for (; i + 4 <= end; i += 4) {
    int r0 = indices[i];
    int r1 = indices[i + 1];
    int r2 = indices[i + 2];
    int r3 = indices[i + 3];
    float4 v0 = *(const float4*)(hid + (size_t)r0 * HDIM + col);
    float4 v1 = *(const float4*)(hid + (size_t)r1 * HDIM + col);
    float4 v2 = *(const float4*)(hid + (size_t)r2 * HDIM + col);
    float4 v3 = *(const float4*)(hid + (size_t)r3 * HDIM + col);
    a0.x += v0.x; a0.y += v0.y; a0.z += v0.z; a0.w += v0.w;
    a1.x += v1.x; a1.y += v1.y; a1.z += v1.z; a1.w += v1.w;
    a2.x += v2.x; a2.y += v2.y; a2.z += v2.z; a2.w += v2.w;
    a3.x += v3.x; a3.y += v3.y; a3.z += v3.z; a3.w += v3.w;
  }
  for (; i < end; ++i) {
    int r = indices[i];
    float4 v = *(const float4*)(hid + (size_t)r * HDIM + col);
    a0.x += v.x; a0.y += v.y; a0.z += v.z; a0.w += v.w;
  }
  a0.x += a1.x + a2.x + a3.x;
  a0.y += a1.y + a2.y + a3.y;
  a0.z += a1.z + a2.z + a3.z;
  a0.w += a1.w + a2.w + a3.w;

  const float inv = 1.0f / fmaxf((float)(end - start), 1.0f);
  ushort4 o;
  o.x = f2bf(a0.x * inv); o.y = f2bf(a0.y * inv);
  o.z = f2bf(a0.z * inv); o.w = f2bf(a0.w * inv);
  *(ushort4*)(hb + (size_t)g * HDIM + col) = o;

  if (t == 0) out[g] = b_proj[0];
}

// ---------------- Kernel 2: fused GEMM + bias + erf-GELU + proj ----------------
// C tile 128x128, BK=64, 512 threads = 8 waves (2m x 4n), wave tile 64x32.
// Grid (x = m-tile 64, y = n-tile 8): linear id = n*64+m -> XCD = m%8, so all 8
// n-blocks of an m-tile co-reside on one XCD; per-XCD L2 working set ~4 MiB
// (8 A-tiles x 256KB + B 2MiB) -> A/B fetched ~once from HBM/L3, reuse from L2.
// LDS row = 8 chunks of 16B; chunk kc stored at slot kc ^ (row&7) (conflict-free reads).
__global__ void __launch_bounds__(512)
gemm_gelu_proj_kernel(const unsigned short* __restrict__ A,   // h  [NSEG,KD] bf16
                      const unsigned short* __restrict__ Bw,  // W  [ND,KD]  bf16
                      const float* __restrict__ b_dense,
                      const float* __restrict__ w_proj,
                      float* __restrict__ out) {
  __shared__ alignas(16) unsigned short As[128 * 64];  // 16 KiB
  __shared__ alignas(16) unsigned short Bs[128 * 64];  // 16 KiB

  const int tid  = threadIdx.x;
  const int lane = tid & 63;
  const int wave = tid >> 6;       // 0..7
  const int wm   = wave >> 2;      // 0..1 -> 64 rows
  const int wn   = wave & 3;       // 0..3 -> 32 cols
  const int m0   = blockIdx.x * 128;
  const int n0   = blockIdx.y * 128;
  const int lr   = lane & 15;
  const int quad = lane >> 4;

  f32x4 acc[4][2];
#pragma unroll
  for (int mi = 0; mi < 4; ++mi)
#pragma unroll
    for (int ni = 0; ni < 2; ++ni) {
      acc[mi][ni][0] = 0.f; acc[mi][ni][1] = 0.f;
      acc[mi][ni][2] = 0.f; acc[mi][ni][3] = 0.f;
    }

  for (int kt = 0; kt < KD / 64; ++kt) {
    const int k0 = kt * 64;
    // A tile: 128x64 bf16 = 1024 chunks of 16B; 2 per thread. Same for B.
#pragma unroll
    for (int j = 0; j < 2; ++j) {
      int c   = j * 512 + wave * 64 + lane;
      int row = c >> 3, sl = c & 7;
      int kcg = sl ^ (row & 7);
      async16(A + (size_t)(m0 + row) * KD + k0 + kcg * 8,
              (char*)As + (j * 512 + wave * 64) * 16);
    }
#pragma unroll
    for (int j = 0; j < 2; ++j) {
      int c   = j * 512 + wave * 64 + lane;
      int row = c >> 3, sl = c & 7;
      int kcg = sl ^ (row & 7);
      async16(Bw + (size_t)(n0 + row) * KD + k0 + kcg * 8,
              (char*)Bs + (j * 512 + wave * 64) * 16);
    }
    __syncthreads();

#pragma unroll
    for (int s = 0; s < 2; ++s) {           // two k-steps of 32
      bf16x8 af[4], bf_[2];
#pragma unroll
      for (int i = 0; i < 4; ++i) {
        int ra   = wm * 64 + i * 16 + lr;
        int slot = (s * 4 + quad) ^ (ra & 7);
        af[i] = *(const bf16x8*)(As + ra * 64 + slot * 8);
      }
#pragma unroll
      for (int i = 0; i < 2; ++i) {
        int rb   = wn * 32 + i * 16 + lr;
        int slot = (s * 4 + quad) ^ (rb & 7);
        bf_[i] = *(const bf16x8*)(Bs + rb * 64 + slot * 8);
      }
#pragma unroll
      for (int mi = 0; mi < 4; ++mi)
#pragma unroll
        for (int ni = 0; ni < 2; ++ni)
          acc[mi][ni] = __builtin_amdgcn_mfma_f32_16x16x32_bf16(af[mi], bf_[ni], acc[mi][ni], 0, 0, 0);
    }
    __syncthreads();
  }

  // Epilogue: bias + exact erf-GELU + w_proj; per-row partial over this wave's 32 cols
#pragma unroll
  for (int mi = 0; mi < 4; ++mi) {
    float rp[4] = {0.f, 0.f, 0.f, 0.f};
#pragma unroll
    for (int ni = 0; ni < 2; ++ni) {
      int col  = n0 + wn * 32 + ni * 16 + lr;
      float bd = b_dense[col];
      float wp = w_proj[col];
#pragma unroll
      for (int r = 0; r < 4; ++r) {
        float v  = acc[mi][ni][r] + bd;
        float gl = 0.5f * v * (1.0f + erff(v * 0.70710678118654752f));
        rp[r] += gl * wp;
      }
    }
#pragma unroll
    for (int r = 0; r < 4; ++r) {
      float c = rp[r];
      c += __shfl_xor(c, 1);
      c += __shfl_xor(c, 2);
      c += __shfl_xor(c, 4);
      c += __shfl_xor(c, 8);
      if (lr == 0)
        atomicAdd(out + (m0 + wm * 64 + mi * 16 + quad * 4 + r), c);
    }
  }
}

extern "C" void kernel_launch(void* const* d_in, const int* in_sizes, int n_in,
                              void* d_out, int out_size, void* d_ws, size_t ws_size,
                              hipStream_t stream) {
  const float* hid     = (const float*)d_in[0];
  const int*   indices = (const int*)d_in[1];
  const int*   seg     = (const int*)d_in[2];
  const float* W_dense = (const float*)d_in[3];
  const float* b_dense = (const float*)d_in[4];
  const float* W_proj  = (const float*)d_in[5];
  const float* b_proj  = (const float*)d_in[6];
  float* out = (float*)d_out;

  // ws layout: h_bf16 [NSEG*KD] (16 MiB) | W_bf16 [ND*KD] (2 MiB) | starts [NSEG+1]
  unsigned short* hb     = (unsigned short*)d_ws;
  unsigned short* Wb     = (unsigned short*)((char*)d_ws + (size_t)NSEG * KD * 2);
  int*            starts = (int*)((char*)d_ws + (size_t)NSEG * KD * 2 + (size_t)ND * KD * 2);

  prep_kernel<<<dim3(1024 + (NIDX + 256) / 256), 256, 0, stream>>>(W_dense, Wb, seg, starts);
  segmean_kernel<<<dim3(NSEG), 256, 0, stream>>>(hid, indices, starts, hb, out, b_proj);
  gemm_gelu_proj_kernel<<<dim3(NSEG / 128, ND / 128), 512, 0, stream>>>(hb, Wb, b_dense, W_proj, out);
}